// Round 1
// baseline (300.705 us; speedup 1.0000x reference)
//
#include <hip/hip_runtime.h>

// Problem constants
#define BB 64
#define NN 512
#define MM 30
#define E2 4
#define NE 32
#define NE4 8
#define NF 64
#define BN_TOTAL (BB * NN)   // 32768

__device__ __forceinline__ float fsig(float x)  { return 1.0f / (1.0f + __expf(-x)); }
__device__ __forceinline__ float ftanh(float x) { return 1.0f - 2.0f / (1.0f + __expf(2.0f * x)); }

// ---------------------------------------------------------------------------
// K1: per-point embedding MLP + bilinear contraction -> D[bn][256]
// 1 wave (64 threads) per block; block handles 2 (b,n) pairs.
// Lane layout: half = lane>>5 selects the pair, n = lane&31 is the m-point
// (only m<30 active for the MLP phase) and later the output column.
// ---------------------------------------------------------------------------
__global__ __launch_bounds__(64) void k_emb(
    const float* __restrict__ Sg, const float* __restrict__ R,
    const float* __restrict__ We0, const float* __restrict__ be0,
    const float* __restrict__ We1, const float* __restrict__ be1,
    const float* __restrict__ We2, const float* __restrict__ be2,
    float* __restrict__ Dout)
{
    __shared__ float G_lds[2][MM][NE];     // 7680 B
    __shared__ float R_lds[2][MM][4];      //  960 B
    __shared__ float A_lds[2][NE4][4];     //  256 B
    __shared__ float Bm_lds[2][4][NE];     // 1024 B

    const int l    = threadIdx.x;
    const int half = l >> 5;
    const int n    = l & 31;
    const int bn   = blockIdx.x * 2 + half;
    const bool act = (n < MM);
    const int m_eff = act ? n : (MM - 1);   // clamp to stay in-bounds

    // Each (b,n,m) point is exactly one float4 in Sg and in R.
    const float4 s4 = ((const float4*)Sg)[(size_t)bn * MM + m_eff];
    const float4 r4 = ((const float4*)R )[(size_t)bn * MM + m_eff];
    const float sg[4] = { s4.x, s4.y, s4.z, s4.w };

    // ---- embedding MLP (per-lane serial, weights wave-uniform -> SGPR) ----
    float h0[NE];
#pragma unroll
    for (int j = 0; j < NE; ++j) {
        float a = be0[j];
#pragma unroll
        for (int i = 0; i < E2; ++i) a += sg[i] * We0[i * NE + j];
        h0[j] = fsig(a);
    }

    float h1[NE];
#pragma unroll
    for (int j = 0; j < NE; ++j) h1[j] = be1[j];
#pragma unroll
    for (int i = 0; i < NE; ++i) {
        const float hi = h0[i];
#pragma unroll
        for (int j = 0; j < NE; ++j) h1[j] += hi * We1[i * NE + j];
    }
#pragma unroll
    for (int j = 0; j < NE; ++j) h1[j] = ftanh(h1[j]);

    float g[NE];
#pragma unroll
    for (int j = 0; j < NE; ++j) g[j] = be2[j];
#pragma unroll
    for (int i = 0; i < NE; ++i) {
        const float hi = h1[i];
#pragma unroll
        for (int j = 0; j < NE; ++j) g[j] += hi * We2[i * NE + j];
    }

    // ---- stage G and R to LDS ----
    if (act) {
#pragma unroll
        for (int q = 0; q < NE / 4; ++q) {
            *(float4*)&G_lds[half][n][4 * q] =
                make_float4(g[4 * q], g[4 * q + 1], g[4 * q + 2], g[4 * q + 3]);
        }
        *(float4*)&R_lds[half][n][0] = r4;
    }
    __syncthreads();

    // ---- Bm[l][n] = sum_m R[m][l] * G[m][n]  (all 64 lanes active) ----
    float bm[4] = {0.f, 0.f, 0.f, 0.f};
#pragma unroll 5
    for (int mm = 0; mm < MM; ++mm) {
        const float gv = G_lds[half][mm][n];
        const float4 rr = *(const float4*)&R_lds[half][mm][0];
        bm[0] += rr.x * gv;
        bm[1] += rr.y * gv;
        bm[2] += rr.z * gv;
        bm[3] += rr.w * gv;
    }
#pragma unroll
    for (int li = 0; li < 4; ++li) Bm_lds[half][li][n] = bm[li];

    // ---- A[k][li] = sum_m G[m][k] * R[m][li]  (32 lanes per half) ----
    {
        const int k  = n & 7;
        const int li = n >> 3;
        float a = 0.f;
#pragma unroll 5
        for (int mm = 0; mm < MM; ++mm)
            a += G_lds[half][mm][k] * R_lds[half][mm][li];
        A_lds[half][k][li] = a;
    }
    __syncthreads();

    // ---- D[k][n] = sum_l A[k][l] * Bm[l][n]; write coalesced ----
    const float4 b0 = make_float4(Bm_lds[half][0][n], Bm_lds[half][1][n],
                                  Bm_lds[half][2][n], Bm_lds[half][3][n]);
#pragma unroll
    for (int k = 0; k < NE4; ++k) {
        const float4 ak = *(const float4*)&A_lds[half][k][0];
        const float d = ak.x * b0.x + ak.y * b0.y + ak.z * b0.z + ak.w * b0.w;
        Dout[(size_t)bn * 256 + k * NE + n] = d;
    }
}

// ---------------------------------------------------------------------------
// K2: fit MLP.  One thread per (b,n).  Weights wave-uniform -> SGPRs.
// ---------------------------------------------------------------------------
__global__ __launch_bounds__(256) void k_fit(
    const float* __restrict__ D,
    const float* __restrict__ Wf0, const float* __restrict__ bf0,
    const float* __restrict__ Wf1, const float* __restrict__ bf1,
    const float* __restrict__ Wf2, const float* __restrict__ bf2,
    const float* __restrict__ Wf3, const float* __restrict__ bf3,
    float* __restrict__ Q)
{
    const int bn = blockIdx.x * blockDim.x + threadIdx.x;
    const float4* __restrict__ d4 = (const float4*)(D + (size_t)bn * 256);

    float h[NF];
#pragma unroll
    for (int f = 0; f < NF; ++f) h[f] = bf0[f];

    // layer 0: 256 -> 64
    for (int kn4 = 0; kn4 < 64; ++kn4) {
        const float4 dv = d4[kn4];
#pragma unroll
        for (int e = 0; e < 4; ++e) {
            const float dval = (&dv.x)[e];
            const float* __restrict__ wrow = Wf0 + (size_t)(kn4 * 4 + e) * NF;
#pragma unroll
            for (int f = 0; f < NF; ++f) h[f] += dval * wrow[f];
        }
    }
#pragma unroll
    for (int f = 0; f < NF; ++f) h[f] = ftanh(h[f]);

    // layer 1: 64 -> 64, sigmoid
    float h2[NF];
#pragma unroll
    for (int f = 0; f < NF; ++f) h2[f] = bf1[f];
#pragma unroll
    for (int gg = 0; gg < NF; ++gg) {
        const float hg = h[gg];
        const float* __restrict__ wrow = Wf1 + (size_t)gg * NF;
#pragma unroll
        for (int f = 0; f < NF; ++f) h2[f] += hg * wrow[f];
    }
#pragma unroll
    for (int f = 0; f < NF; ++f) h2[f] = fsig(h2[f]);

    // layer 2: 64 -> 64, tanh
#pragma unroll
    for (int f = 0; f < NF; ++f) h[f] = bf2[f];
#pragma unroll
    for (int gg = 0; gg < NF; ++gg) {
        const float hg = h2[gg];
        const float* __restrict__ wrow = Wf2 + (size_t)gg * NF;
#pragma unroll
        for (int f = 0; f < NF; ++f) h[f] += hg * wrow[f];
    }
#pragma unroll
    for (int f = 0; f < NF; ++f) h[f] = ftanh(h[f]);

    // layer 3: 64 -> 1
    float q = bf3[0];
#pragma unroll
    for (int gg = 0; gg < NF; ++gg) q += h[gg] * Wf3[gg];

    Q[bn] = q;
}

// ---------------------------------------------------------------------------
// K3: deterministic mean over N per batch element.
// ---------------------------------------------------------------------------
__global__ __launch_bounds__(256) void k_mean(const float* __restrict__ Q,
                                              float* __restrict__ out)
{
    __shared__ float s[256];
    const int b = blockIdx.x;
    const int t = threadIdx.x;
    float v = Q[b * NN + t] + Q[b * NN + 256 + t];
    s[t] = v;
    __syncthreads();
#pragma unroll
    for (int off = 128; off > 0; off >>= 1) {
        if (t < off) s[t] += s[t + off];
        __syncthreads();
    }
    if (t == 0) out[b] = s[0] * (1.0f / (float)NN);
}

// ---------------------------------------------------------------------------
extern "C" void kernel_launch(void* const* d_in, const int* in_sizes, int n_in,
                              void* d_out, int out_size, void* d_ws, size_t ws_size,
                              hipStream_t stream)
{
    const float* Sg  = (const float*)d_in[0];
    const float* R   = (const float*)d_in[1];
    const float* We0 = (const float*)d_in[2];
    const float* be0 = (const float*)d_in[3];
    const float* We1 = (const float*)d_in[4];
    const float* be1 = (const float*)d_in[5];
    const float* We2 = (const float*)d_in[6];
    const float* be2 = (const float*)d_in[7];
    const float* Wf0 = (const float*)d_in[8];
    const float* bf0 = (const float*)d_in[9];
    const float* Wf1 = (const float*)d_in[10];
    const float* bf1 = (const float*)d_in[11];
    const float* Wf2 = (const float*)d_in[12];
    const float* bf2 = (const float*)d_in[13];
    const float* Wf3 = (const float*)d_in[14];
    const float* bf3 = (const float*)d_in[15];

    float* D = (float*)d_ws;                                  // 32768*256 floats = 33.55 MB
    float* Q = (float*)((char*)d_ws + (size_t)BN_TOTAL * 256 * sizeof(float)); // 128 KB

    k_emb<<<BN_TOTAL / 2, 64, 0, stream>>>(Sg, R, We0, be0, We1, be1, We2, be2, D);
    k_fit<<<BN_TOTAL / 256, 256, 0, stream>>>(D, Wf0, bf0, Wf1, bf1, Wf2, bf2, Wf3, bf3, Q);
    k_mean<<<BB, 256, 0, stream>>>(Q, (float*)d_out);
}

// Round 2
// 209.764 us; speedup vs baseline: 1.4335x; 1.4335x over previous
//
#include <hip/hip_runtime.h>

// Problem constants
#define BB 64
#define NN 512
#define MM 30
#define E2 4
#define NE 32
#define NE4 8
#define NF 64
#define BN_TOTAL (BB * NN)   // 32768

__device__ __forceinline__ float fsig(float x)  { return 1.0f / (1.0f + __expf(-x)); }
__device__ __forceinline__ float ftanh(float x) { return 1.0f - 2.0f / (1.0f + __expf(2.0f * x)); }

// ---------------------------------------------------------------------------
// K1: per-point embedding MLP + bilinear contraction -> D[bn][256]
// 1 wave (64 threads) per block; block handles 2 (b,n) pairs.
// ---------------------------------------------------------------------------
__global__ __launch_bounds__(64) void k_emb(
    const float* __restrict__ Sg, const float* __restrict__ R,
    const float* __restrict__ We0, const float* __restrict__ be0,
    const float* __restrict__ We1, const float* __restrict__ be1,
    const float* __restrict__ We2, const float* __restrict__ be2,
    float* __restrict__ Dout)
{
    __shared__ float G_lds[2][MM][NE];     // 7680 B
    __shared__ float R_lds[2][MM][4];      //  960 B
    __shared__ float A_lds[2][NE4][4];     //  256 B
    __shared__ float Bm_lds[2][4][NE];     // 1024 B

    const int l    = threadIdx.x;
    const int half = l >> 5;
    const int n    = l & 31;
    const int bn   = blockIdx.x * 2 + half;
    const bool act = (n < MM);
    const int m_eff = act ? n : (MM - 1);   // clamp to stay in-bounds

    const float4 s4 = ((const float4*)Sg)[(size_t)bn * MM + m_eff];
    const float4 r4 = ((const float4*)R )[(size_t)bn * MM + m_eff];
    const float sg[4] = { s4.x, s4.y, s4.z, s4.w };

    // ---- embedding MLP (per-lane serial, weights wave-uniform -> SGPR) ----
    float h0[NE];
#pragma unroll
    for (int j = 0; j < NE; ++j) {
        float a = be0[j];
#pragma unroll
        for (int i = 0; i < E2; ++i) a += sg[i] * We0[i * NE + j];
        h0[j] = fsig(a);
    }

    float h1[NE];
#pragma unroll
    for (int j = 0; j < NE; ++j) h1[j] = be1[j];
#pragma unroll
    for (int i = 0; i < NE; ++i) {
        const float hi = h0[i];
#pragma unroll
        for (int j = 0; j < NE; ++j) h1[j] += hi * We1[i * NE + j];
    }
#pragma unroll
    for (int j = 0; j < NE; ++j) h1[j] = ftanh(h1[j]);

    float g[NE];
#pragma unroll
    for (int j = 0; j < NE; ++j) g[j] = be2[j];
#pragma unroll
    for (int i = 0; i < NE; ++i) {
        const float hi = h1[i];
#pragma unroll
        for (int j = 0; j < NE; ++j) g[j] += hi * We2[i * NE + j];
    }

    // ---- stage G and R to LDS ----
    if (act) {
#pragma unroll
        for (int q = 0; q < NE / 4; ++q) {
            *(float4*)&G_lds[half][n][4 * q] =
                make_float4(g[4 * q], g[4 * q + 1], g[4 * q + 2], g[4 * q + 3]);
        }
        *(float4*)&R_lds[half][n][0] = r4;
    }
    __syncthreads();

    // ---- Bm[l][n] = sum_m R[m][l] * G[m][n] ----
    float bm[4] = {0.f, 0.f, 0.f, 0.f};
#pragma unroll 5
    for (int mm = 0; mm < MM; ++mm) {
        const float gv = G_lds[half][mm][n];
        const float4 rr = *(const float4*)&R_lds[half][mm][0];
        bm[0] += rr.x * gv;
        bm[1] += rr.y * gv;
        bm[2] += rr.z * gv;
        bm[3] += rr.w * gv;
    }
#pragma unroll
    for (int li = 0; li < 4; ++li) Bm_lds[half][li][n] = bm[li];

    // ---- A[k][li] = sum_m G[m][k] * R[m][li] ----
    {
        const int k  = n & 7;
        const int li = n >> 3;
        float a = 0.f;
#pragma unroll 5
        for (int mm = 0; mm < MM; ++mm)
            a += G_lds[half][mm][k] * R_lds[half][mm][li];
        A_lds[half][k][li] = a;
    }
    __syncthreads();

    // ---- D[k][n] = sum_l A[k][l] * Bm[l][n]; write coalesced ----
    const float4 b0 = make_float4(Bm_lds[half][0][n], Bm_lds[half][1][n],
                                  Bm_lds[half][2][n], Bm_lds[half][3][n]);
#pragma unroll
    for (int k = 0; k < NE4; ++k) {
        const float4 ak = *(const float4*)&A_lds[half][k][0];
        const float d = ak.x * b0.x + ak.y * b0.y + ak.z * b0.z + ak.w * b0.w;
        Dout[(size_t)bn * 256 + k * NE + n] = d;
    }
}

// ---------------------------------------------------------------------------
// K2 v2: fit MLP, feature-split waves.
// Block = 256 threads = 4 waves, handles 64 rows (bn).
// Wave fq owns features [fq*16, fq*16+16); lane = row within block.
// Weight addresses are wave-uniform -> SGPR broadcast (s_load).
// Hidden activations exchanged through transposed LDS tiles HT[f][row]
// (lane-consecutive -> conflict-free, coalesced).
// ---------------------------------------------------------------------------
__global__ __launch_bounds__(256) void k_fit2(
    const float* __restrict__ D,
    const float* __restrict__ Wf0, const float* __restrict__ bf0,
    const float* __restrict__ Wf1, const float* __restrict__ bf1,
    const float* __restrict__ Wf2, const float* __restrict__ bf2,
    const float* __restrict__ Wf3, const float* __restrict__ bf3,
    float* __restrict__ Q)
{
    __shared__ float HT0[64 * 64];   // 16 KB, [f][row]
    __shared__ float HT1[64 * 64];   // 16 KB, [f][row]

    const int tid = threadIdx.x;
    const int fq  = tid >> 6;          // wave id: feature quarter 0..3
    const int r   = tid & 63;          // lane: row within block
    const int row = blockIdx.x * 64 + r;
    const int f0  = fq * 16;

    // ---- layer 0: 256 -> 64 (this wave: 16 features), k order preserved ----
    float h[16];
#pragma unroll
    for (int j = 0; j < 16; ++j) h[j] = bf0[f0 + j];

    const float4* __restrict__ d4 = (const float4*)(D + (size_t)row * 256);
#pragma unroll 8
    for (int kk = 0; kk < 64; ++kk) {
        const float4 dv = d4[kk];
#pragma unroll
        for (int e = 0; e < 4; ++e) {
            const float dval = (&dv.x)[e];
            const float* __restrict__ w = Wf0 + (size_t)(kk * 4 + e) * NF + f0;
#pragma unroll
            for (int j = 0; j < 16; ++j) h[j] += dval * w[j];
        }
    }
#pragma unroll
    for (int j = 0; j < 16; ++j) HT0[(f0 + j) * 64 + r] = ftanh(h[j]);
    __syncthreads();

    // ---- layer 1: 64 -> 64, sigmoid ----
    float h2[16];
#pragma unroll
    for (int j = 0; j < 16; ++j) h2[j] = bf1[f0 + j];
#pragma unroll 8
    for (int k = 0; k < 64; ++k) {
        const float hv = HT0[k * 64 + r];
        const float* __restrict__ w = Wf1 + (size_t)k * NF + f0;
#pragma unroll
        for (int j = 0; j < 16; ++j) h2[j] += hv * w[j];
    }
#pragma unroll
    for (int j = 0; j < 16; ++j) HT1[(f0 + j) * 64 + r] = fsig(h2[j]);
    __syncthreads();

    // ---- layer 2: 64 -> 64, tanh (results stay in registers) ----
#pragma unroll
    for (int j = 0; j < 16; ++j) h[j] = bf2[f0 + j];
#pragma unroll 8
    for (int k = 0; k < 64; ++k) {
        const float hv = HT1[k * 64 + r];
        const float* __restrict__ w = Wf2 + (size_t)k * NF + f0;
#pragma unroll
        for (int j = 0; j < 16; ++j) h[j] += hv * w[j];
    }

    // ---- layer 3 partial: this wave's 16 features ----
    float qp = 0.f;
#pragma unroll
    for (int j = 0; j < 16; ++j) qp += ftanh(h[j]) * Wf3[f0 + j];

    // HT0 is dead after the L0->L1 sync completed its reads; safe to reuse.
    float* Qp = HT0;
    Qp[fq * 64 + r] = qp;
    __syncthreads();

    if (tid < 64) {
        const float q = bf3[0] + Qp[tid] + Qp[64 + tid] + Qp[128 + tid] + Qp[192 + tid];
        Q[(size_t)blockIdx.x * 64 + tid] = q;
    }
}

// ---------------------------------------------------------------------------
// K3: deterministic mean over N per batch element.
// ---------------------------------------------------------------------------
__global__ __launch_bounds__(256) void k_mean(const float* __restrict__ Q,
                                              float* __restrict__ out)
{
    __shared__ float s[256];
    const int b = blockIdx.x;
    const int t = threadIdx.x;
    float v = Q[b * NN + t] + Q[b * NN + 256 + t];
    s[t] = v;
    __syncthreads();
#pragma unroll
    for (int off = 128; off > 0; off >>= 1) {
        if (t < off) s[t] += s[t + off];
        __syncthreads();
    }
    if (t == 0) out[b] = s[0] * (1.0f / (float)NN);
}

// ---------------------------------------------------------------------------
extern "C" void kernel_launch(void* const* d_in, const int* in_sizes, int n_in,
                              void* d_out, int out_size, void* d_ws, size_t ws_size,
                              hipStream_t stream)
{
    const float* Sg  = (const float*)d_in[0];
    const float* R   = (const float*)d_in[1];
    const float* We0 = (const float*)d_in[2];
    const float* be0 = (const float*)d_in[3];
    const float* We1 = (const float*)d_in[4];
    const float* be1 = (const float*)d_in[5];
    const float* We2 = (const float*)d_in[6];
    const float* be2 = (const float*)d_in[7];
    const float* Wf0 = (const float*)d_in[8];
    const float* bf0 = (const float*)d_in[9];
    const float* Wf1 = (const float*)d_in[10];
    const float* bf1 = (const float*)d_in[11];
    const float* Wf2 = (const float*)d_in[12];
    const float* bf2 = (const float*)d_in[13];
    const float* Wf3 = (const float*)d_in[14];
    const float* bf3 = (const float*)d_in[15];

    float* D = (float*)d_ws;                                  // 33.55 MB
    float* Q = (float*)((char*)d_ws + (size_t)BN_TOTAL * 256 * sizeof(float)); // 128 KB

    k_emb<<<BN_TOTAL / 2, 64, 0, stream>>>(Sg, R, We0, be0, We1, be1, We2, be2, D);
    k_fit2<<<BN_TOTAL / 64, 256, 0, stream>>>(D, Wf0, bf0, Wf1, bf1, Wf2, bf2, Wf3, bf3, Q);
    k_mean<<<BB, 256, 0, stream>>>(Q, (float*)d_out);
}

// Round 3
// 129.401 us; speedup vs baseline: 2.3238x; 1.6210x over previous
//
#include <hip/hip_runtime.h>

// Problem constants
#define BB 64
#define NN 512
#define MM 30
#define E2 4
#define NE 32
#define NE4 8
#define NF 64
#define BN_TOTAL (BB * NN)   // 32768

__device__ __forceinline__ float fsig(float x)  { return 1.0f / (1.0f + __expf(-x)); }
__device__ __forceinline__ float ftanh(float x) { return 1.0f - 2.0f / (1.0f + __expf(2.0f * x)); }

// ---------------------------------------------------------------------------
// K1: per-point embedding MLP + bilinear contraction -> D[bn][256]
// 1 wave (64 threads) per block; block handles 2 (b,n) pairs.
// __launch_bounds__(64,2): allow up to ~256 VGPRs so h0/h1/g (96 live floats)
// stay in registers instead of spilling to scratch. Occupancy is LDS-limited
// (~15 blocks/CU), so the relaxed VGPR cap costs nothing.
// ---------------------------------------------------------------------------
__global__ __launch_bounds__(64, 2) void k_emb(
    const float* __restrict__ Sg, const float* __restrict__ R,
    const float* __restrict__ We0, const float* __restrict__ be0,
    const float* __restrict__ We1, const float* __restrict__ be1,
    const float* __restrict__ We2, const float* __restrict__ be2,
    float* __restrict__ Dout)
{
    __shared__ float G_lds[2][MM][NE];     // 7680 B
    __shared__ float R_lds[2][MM][4];      //  960 B
    __shared__ float A_lds[2][NE4][4];     //  256 B
    __shared__ float Bm_lds[2][4][NE];     // 1024 B

    const int l    = threadIdx.x;
    const int half = l >> 5;
    const int n    = l & 31;
    const int bn   = blockIdx.x * 2 + half;
    const bool act = (n < MM);
    const int m_eff = act ? n : (MM - 1);   // clamp to stay in-bounds

    const float4 s4 = ((const float4*)Sg)[(size_t)bn * MM + m_eff];
    const float4 r4 = ((const float4*)R )[(size_t)bn * MM + m_eff];
    const float sg[4] = { s4.x, s4.y, s4.z, s4.w };

    // ---- embedding MLP (per-lane serial, weights truly uniform -> s_load) ----
    float h0[NE];
#pragma unroll
    for (int j = 0; j < NE; ++j) {
        float a = be0[j];
#pragma unroll
        for (int i = 0; i < E2; ++i) a += sg[i] * We0[i * NE + j];
        h0[j] = fsig(a);
    }

    float h1[NE];
#pragma unroll
    for (int j = 0; j < NE; ++j) h1[j] = be1[j];
#pragma unroll
    for (int i = 0; i < NE; ++i) {
        const float hi = h0[i];
#pragma unroll
        for (int j = 0; j < NE; ++j) h1[j] += hi * We1[i * NE + j];
    }
#pragma unroll
    for (int j = 0; j < NE; ++j) h1[j] = ftanh(h1[j]);

    float g[NE];
#pragma unroll
    for (int j = 0; j < NE; ++j) g[j] = be2[j];
#pragma unroll
    for (int i = 0; i < NE; ++i) {
        const float hi = h1[i];
#pragma unroll
        for (int j = 0; j < NE; ++j) g[j] += hi * We2[i * NE + j];
    }

    // ---- stage G and R to LDS ----
    if (act) {
#pragma unroll
        for (int q = 0; q < NE / 4; ++q) {
            *(float4*)&G_lds[half][n][4 * q] =
                make_float4(g[4 * q], g[4 * q + 1], g[4 * q + 2], g[4 * q + 3]);
        }
        *(float4*)&R_lds[half][n][0] = r4;
    }
    __syncthreads();

    // ---- Bm[l][n] = sum_m R[m][l] * G[m][n] ----
    float bm[4] = {0.f, 0.f, 0.f, 0.f};
#pragma unroll 5
    for (int mm = 0; mm < MM; ++mm) {
        const float gv = G_lds[half][mm][n];
        const float4 rr = *(const float4*)&R_lds[half][mm][0];
        bm[0] += rr.x * gv;
        bm[1] += rr.y * gv;
        bm[2] += rr.z * gv;
        bm[3] += rr.w * gv;
    }
#pragma unroll
    for (int li = 0; li < 4; ++li) Bm_lds[half][li][n] = bm[li];

    // ---- A[k][li] = sum_m G[m][k] * R[m][li] ----
    {
        const int k  = n & 7;
        const int li = n >> 3;
        float a = 0.f;
#pragma unroll 5
        for (int mm = 0; mm < MM; ++mm)
            a += G_lds[half][mm][k] * R_lds[half][mm][li];
        A_lds[half][k][li] = a;
    }
    __syncthreads();

    // ---- D[k][n] = sum_l A[k][l] * Bm[l][n]; write coalesced ----
    const float4 b0 = make_float4(Bm_lds[half][0][n], Bm_lds[half][1][n],
                                  Bm_lds[half][2][n], Bm_lds[half][3][n]);
#pragma unroll
    for (int k = 0; k < NE4; ++k) {
        const float4 ak = *(const float4*)&A_lds[half][k][0];
        const float d = ak.x * b0.x + ak.y * b0.y + ak.z * b0.z + ak.w * b0.w;
        Dout[(size_t)bn * 256 + k * NE + n] = d;
    }
}

// ---------------------------------------------------------------------------
// K2 v3: fit MLP, feature-split waves + PROVABLY-UNIFORM weight addressing.
// Block = 256 threads = 4 waves, 64 rows. Wave fq owns features
// [fq*16, fq*16+16). f0 is pinned to an SGPR via readfirstlane so every
// weight/bias access compiles to s_load (scalar pipe, constant-cache),
// leaving the VALU free to do 16 FMAs per s_load_dwordx16.
// ---------------------------------------------------------------------------
__global__ __launch_bounds__(256) void k_fit2(
    const float* __restrict__ D,
    const float* __restrict__ Wf0, const float* __restrict__ bf0,
    const float* __restrict__ Wf1, const float* __restrict__ bf1,
    const float* __restrict__ Wf2, const float* __restrict__ bf2,
    const float* __restrict__ Wf3, const float* __restrict__ bf3,
    float* __restrict__ Q)
{
    __shared__ float HT0[64 * 64];   // 16 KB, [f][row]
    __shared__ float HT1[64 * 64];   // 16 KB, [f][row]

    const int tid = threadIdx.x;
    const int r   = tid & 63;          // lane: row within block
    const int row = blockIdx.x * 64 + r;
    // Wave-uniform feature base, pinned to SGPR so the compiler proves it.
    const int f0  = __builtin_amdgcn_readfirstlane(tid >> 6) * 16;

    // ---- layer 0: 256 -> 64 (this wave: 16 features), k order preserved ----
    float h[16];
#pragma unroll
    for (int j = 0; j < 16; ++j) h[j] = bf0[f0 + j];

    const float4* __restrict__ d4 = (const float4*)(D + (size_t)row * 256);
#pragma unroll 8
    for (int kk = 0; kk < 64; ++kk) {
        const float4 dv = d4[kk];
#pragma unroll
        for (int e = 0; e < 4; ++e) {
            const float dval = (&dv.x)[e];
            const float* __restrict__ w = Wf0 + (size_t)(kk * 4 + e) * NF + f0;
#pragma unroll
            for (int j = 0; j < 16; ++j) h[j] += dval * w[j];
        }
    }
#pragma unroll
    for (int j = 0; j < 16; ++j) HT0[(f0 + j) * 64 + r] = ftanh(h[j]);
    __syncthreads();

    // ---- layer 1: 64 -> 64, sigmoid ----
    float h2[16];
#pragma unroll
    for (int j = 0; j < 16; ++j) h2[j] = bf1[f0 + j];
#pragma unroll 8
    for (int k = 0; k < 64; ++k) {
        const float hv = HT0[k * 64 + r];
        const float* __restrict__ w = Wf1 + (size_t)k * NF + f0;
#pragma unroll
        for (int j = 0; j < 16; ++j) h2[j] += hv * w[j];
    }
#pragma unroll
    for (int j = 0; j < 16; ++j) HT1[(f0 + j) * 64 + r] = fsig(h2[j]);
    __syncthreads();

    // ---- layer 2: 64 -> 64, tanh (results stay in registers) ----
#pragma unroll
    for (int j = 0; j < 16; ++j) h[j] = bf2[f0 + j];
#pragma unroll 8
    for (int k = 0; k < 64; ++k) {
        const float hv = HT1[k * 64 + r];
        const float* __restrict__ w = Wf2 + (size_t)k * NF + f0;
#pragma unroll
        for (int j = 0; j < 16; ++j) h[j] += hv * w[j];
    }

    // ---- layer 3 partial: this wave's 16 features ----
    float qp = 0.f;
#pragma unroll
    for (int j = 0; j < 16; ++j) qp += ftanh(h[j]) * Wf3[f0 + j];

    // HT0 is dead (all reads completed before the HT1 barrier); reuse it.
    float* Qp = HT0;
    Qp[(tid >> 6) * 64 + r] = qp;
    __syncthreads();

    if (tid < 64) {
        const float q = bf3[0] + Qp[tid] + Qp[64 + tid] + Qp[128 + tid] + Qp[192 + tid];
        Q[(size_t)blockIdx.x * 64 + tid] = q;
    }
}

// ---------------------------------------------------------------------------
// K3: deterministic mean over N per batch element.
// ---------------------------------------------------------------------------
__global__ __launch_bounds__(256) void k_mean(const float* __restrict__ Q,
                                              float* __restrict__ out)
{
    __shared__ float s[256];
    const int b = blockIdx.x;
    const int t = threadIdx.x;
    float v = Q[b * NN + t] + Q[b * NN + 256 + t];
    s[t] = v;
    __syncthreads();
#pragma unroll
    for (int off = 128; off > 0; off >>= 1) {
        if (t < off) s[t] += s[t + off];
        __syncthreads();
    }
    if (t == 0) out[b] = s[0] * (1.0f / (float)NN);
}

// ---------------------------------------------------------------------------
extern "C" void kernel_launch(void* const* d_in, const int* in_sizes, int n_in,
                              void* d_out, int out_size, void* d_ws, size_t ws_size,
                              hipStream_t stream)
{
    const float* Sg  = (const float*)d_in[0];
    const float* R   = (const float*)d_in[1];
    const float* We0 = (const float*)d_in[2];
    const float* be0 = (const float*)d_in[3];
    const float* We1 = (const float*)d_in[4];
    const float* be1 = (const float*)d_in[5];
    const float* We2 = (const float*)d_in[6];
    const float* be2 = (const float*)d_in[7];
    const float* Wf0 = (const float*)d_in[8];
    const float* bf0 = (const float*)d_in[9];
    const float* Wf1 = (const float*)d_in[10];
    const float* bf1 = (const float*)d_in[11];
    const float* Wf2 = (const float*)d_in[12];
    const float* bf2 = (const float*)d_in[13];
    const float* Wf3 = (const float*)d_in[14];
    const float* bf3 = (const float*)d_in[15];

    float* D = (float*)d_ws;                                  // 33.55 MB
    float* Q = (float*)((char*)d_ws + (size_t)BN_TOTAL * 256 * sizeof(float)); // 128 KB

    k_emb<<<BN_TOTAL / 2, 64, 0, stream>>>(Sg, R, We0, be0, We1, be1, We2, be2, D);
    k_fit2<<<BN_TOTAL / 64, 256, 0, stream>>>(D, Wf0, bf0, Wf1, bf1, Wf2, bf2, Wf3, bf3, Q);
    k_mean<<<BB, 256, 0, stream>>>(Q, (float*)d_out);
}